// Round 14
// baseline (577.864 us; speedup 1.0000x reference)
//
#include <hip/hip_runtime.h>
#include <hip/hip_bf16.h>

#define BIG 1e30f

typedef __attribute__((ext_vector_type(8))) short short8;
typedef __attribute__((ext_vector_type(4))) float f32x4;

#define LGKM_FENCE() do { asm volatile("s_waitcnt lgkmcnt(0)" ::: "memory"); \
                          __builtin_amdgcn_sched_barrier(0); } while (0)
#define SCHED_FENCE() __builtin_amdgcn_sched_barrier(0)

__device__ __forceinline__ unsigned pk_bf16(float lo, float hi) {
    unsigned r;
    asm("v_cvt_pk_bf16_f32 %0, %1, %2" : "=v"(r) : "v"(lo), "v"(hi));
    return r;
}

__device__ __forceinline__ short8 make_frag(float4 a, float4 c) {
    union { unsigned u[4]; short8 s; } cv;
    cv.u[0] = pk_bf16(a.x, a.y);
    cv.u[1] = pk_bf16(a.z, a.w);
    cv.u[2] = pk_bf16(c.x, c.y);
    cv.u[3] = pk_bf16(c.z, c.w);
    return cv.s;
}

// shfl_up(v,1) via DPP wave_shr:1 (validated round 7, absmax 0.0).
__device__ __forceinline__ float dpp_shr1(float v) {
    int o = __builtin_amdgcn_update_dpp(__float_as_int(v), __float_as_int(v),
                                        0x138, 0xf, 0xf, false);
    return __int_as_float(o);
}

// ROUND 14: same-wave GEMM-ahead pipelining + readlane rowv.
// 8 waves, 512 thr (VGPR cap 256 — r13's 16-wave split capped at 64 -> spills).
// Per stage s, wave w: (a) issue B-loads + MFMAs for tile (w, s+1-w) into acc,
// interleaved between the DP chunks of tile (w, s-w) (MFMA pipe overlaps the
// chain's stalls); (b) epilogue acc->Dt[w] AFTER the DP (panel is wave-private
// -> no double buffer, no extra barrier). Virtual stage s=-1 pre-produces
// tile (0,0) through the same serial path. rowv: lane l holds cv=rowR[1+l];
// step kk takes readlane(cv, kk&63) -> 128 uniform LDS reads/stage removed.
// DP chain semantics bit-identical to r9 (absmax 0.0 lineage).
__global__ __launch_bounds__(512, 1) void dtw_fused(const float* __restrict__ x,
                                                    const float* __restrict__ y,
                                                    float* __restrict__ out)
{
    __shared__ float Dt[8][4096];      // per-wave 64x64 f32 D-tile, XOR-swizzled
    __shared__ float y2s[512];
    __shared__ float rowA[3][8][65];   // [parity][tj][0]=corner, [1+j]=bottom row

    const int b   = blockIdx.x;
    const int tid = threadIdx.x;
    const int w   = tid >> 6;
    const int l   = tid & 63;

    const float* xb = x + (size_t)b * 512 * 64;
    const float* yb = y + (size_t)b * 512 * 64;

    // ---------- prologue: y2, rowA init ----------
    {
        const float4* yr = reinterpret_cast<const float4*>(yb + (size_t)tid * 64);
        float s = 0.f;
        #pragma unroll
        for (int q = 0; q < 16; ++q) {
            float4 v = yr[q];
            s += v.x*v.x + v.y*v.y + v.z*v.z + v.w*v.w;
        }
        y2s[tid] = s;
    }
    for (int i = tid; i < 3*8*65; i += 512) {
        ((float*)rowA)[i] = (i == 2*8*65) ? 0.0f : BIG;
    }

    // ---------- prologue: A fragments (bf16) + x2 ----------
    const int lr = l & 15;
    const int lg = l >> 4;
    short8 afr[4][2];
    float  x2c[4][4];
    {
        float x2f[4];
        #pragma unroll
        for (int mi = 0; mi < 4; ++mi) {
            float part = 0.f;
            #pragma unroll
            for (int ks = 0; ks < 2; ++ks) {
                const float* rp = xb + (size_t)(w*64 + mi*16 + lr) * 64 + ks*32 + lg*8;
                float4 a0 = *reinterpret_cast<const float4*>(rp);
                float4 a1 = *reinterpret_cast<const float4*>(rp + 4);
                afr[mi][ks] = make_frag(a0, a1);
                part += a0.x*a0.x + a0.y*a0.y + a0.z*a0.z + a0.w*a0.w
                      + a1.x*a1.x + a1.y*a1.y + a1.z*a1.z + a1.w*a1.w;
            }
            part += __shfl_xor(part, 16);
            part += __shfl_xor(part, 32);
            x2f[mi] = part;
        }
        #pragma unroll
        for (int mi = 0; mi < 4; ++mi)
            #pragma unroll
            for (int i = 0; i < 4; ++i)
                x2c[mi][i] = __shfl(x2f[mi], lg*4 + i);
    }
    __syncthreads();   // y2s/rowA ready

    float* Dw = Dt[w];
    const int xr4 = (l & 7) << 2;
    float colreg = BIG;

    #pragma unroll 1
    for (int s = -1; s < 15; ++s) {
        __syncthreads();
        const int tj  = s - w;                     // current DP tile col
        const int tjn = s + 1 - w;                 // next GEMM tile col
        const bool dact = ((unsigned)tj  <= 7u);
        const bool gact = ((unsigned)tjn <= 7u) && (s < 14);
        const int j0n = tjn * 64;

        f32x4 acc[4][4] = {};
        float4 bw0[4], bw1[4], bw2[4], bw3[4];

        auto issueB = [&](float4 (&bw)[4], int ni) {
            const float* rp = yb + (size_t)(j0n + ni*16 + lr) * 64 + lg*8;
            bw[0] = *reinterpret_cast<const float4*>(rp);
            bw[1] = *reinterpret_cast<const float4*>(rp + 4);
            bw[2] = *reinterpret_cast<const float4*>(rp + 32);
            bw[3] = *reinterpret_cast<const float4*>(rp + 36);
        };
        auto mfmaB = [&](float4 (&bw)[4], int ni) {
            short8 f0 = make_frag(bw[0], bw[1]);
            short8 f1 = make_frag(bw[2], bw[3]);
            #pragma unroll
            for (int mi = 0; mi < 4; ++mi) {
                acc[mi][ni] = __builtin_amdgcn_mfma_f32_16x16x32_bf16(afr[mi][0], f0, acc[mi][ni], 0, 0, 0);
                acc[mi][ni] = __builtin_amdgcn_mfma_f32_16x16x32_bf16(afr[mi][1], f1, acc[mi][ni], 0, 0, 0);
            }
        };
        auto epi = [&]() {
            #pragma unroll
            for (int ni = 0; ni < 4; ++ni) {
                float y2v = y2s[j0n + ni*16 + lr];
                #pragma unroll
                for (int mi = 0; mi < 4; ++mi) {
                    #pragma unroll
                    for (int i = 0; i < 4; ++i) {
                        int row = mi*16 + lg*4 + i;
                        int col = ni*16 + lr;
                        Dw[(row*64 + col) ^ ((row & 7) << 2)] = x2c[mi][i] + y2v - 2.0f * acc[mi][ni][i];
                    }
                }
            }
        };

        if (dact) {
            const float* rowR = rowA[(s + 2) % 3][tj];
            float*       rowW = rowA[s % 3][tj];

            if (tj == 0 && l == 0) rowW[0] = BIG;

            float cv    = rowR[1 + l];    // conveyor: lane l holds up-row col l
            float saved = rowR[0];        // corner / rolling R[row-1][c-1] for lane 0
            float r1 = colreg;
            float r2 = BIG;
            float colnext = BIG;

            auto issue_dv = [&](float (&dvb)[16], int k0) {
                #pragma unroll
                for (int u = 0; u < 16; ++u)
                    dvb[u] = Dw[(l << 6) + (((k0 + u - l) & 63) ^ xr4)];
            };
            auto compute16 = [&](float (&dvb)[16], int k0) {
                float rw[16];
                #pragma unroll
                for (int u = 0; u < 16; ++u) {
                    int   kk   = k0 + u;
                    int   c    = kk - l;
                    float rowv = __int_as_float(
                        __builtin_amdgcn_readlane(__float_as_int(cv), kk & 63));
                    float dv   = dvb[u];
                    float up   = dpp_shr1(r1);
                    float dg   = dpp_shr1(r2);
                    float pu   = (l == 0) ? rowv  : up;
                    float pd   = (l == 0) ? saved : dg;
                    float nv   = dv + fminf(fminf(pd, pu), r1);
                    bool  act  = ((unsigned)c) < 64u;
                    r2 = act ? r1 : r2;
                    r1 = act ? nv : r1;
                    colnext = (c == 63) ? nv : colnext;
                    rw[u] = nv;
                    saved = rowv;
                }
                if (l == 63) {
                    #pragma unroll
                    for (int u = 0; u < 16; ++u) {
                        int kk = k0 + u;
                        if ((unsigned)(kk - 63) < 64u) rowW[kk - 62] = rw[u];
                    }
                }
            };

            float dvbA[16], dvbB[16];
            issue_dv(dvbA, 0);
            if (gact) issueB(bw0, 0);
            LGKM_FENCE();
            issue_dv(dvbB, 16);  SCHED_FENCE();  compute16(dvbA, 0);
            if (gact) issueB(bw1, 1);            LGKM_FENCE();
            issue_dv(dvbA, 32);  SCHED_FENCE();  compute16(dvbB, 16);
            if (gact) mfmaB(bw0, 0);             LGKM_FENCE();
            issue_dv(dvbB, 48);  SCHED_FENCE();  compute16(dvbA, 32);
            if (gact) issueB(bw2, 2);            LGKM_FENCE();
            issue_dv(dvbA, 64);  SCHED_FENCE();  compute16(dvbB, 48);
            if (gact) mfmaB(bw1, 1);             LGKM_FENCE();
            issue_dv(dvbB, 80);  SCHED_FENCE();  compute16(dvbA, 64);
            if (gact) issueB(bw3, 3);            LGKM_FENCE();
            issue_dv(dvbA, 96);  SCHED_FENCE();  compute16(dvbB, 80);
            if (gact) mfmaB(bw2, 2);             LGKM_FENCE();
            issue_dv(dvbB, 112); SCHED_FENCE();  compute16(dvbA, 96);
            LGKM_FENCE();
            SCHED_FENCE();       compute16(dvbB, 112);
            if (gact) mfmaB(bw3, 3);             LGKM_FENCE();

            colreg = colnext;
            if (l == 63 && tj < 7) rowA[(s + 1) % 3][tj + 1][0] = colnext;
            if (gact) epi();
        } else if (gact) {
            // serial GEMM (first tile of this wave; includes virtual stage -1)
            issueB(bw0, 0); issueB(bw1, 1); issueB(bw2, 2); issueB(bw3, 3);
            mfmaB(bw0, 0);  mfmaB(bw1, 1);  mfmaB(bw2, 2);  mfmaB(bw3, 3);
            epi();
        }
    }

    if (w == 7 && l == 63) out[b] = colreg;   // R[511][511]
}

extern "C" void kernel_launch(void* const* d_in, const int* in_sizes, int n_in,
                              void* d_out, int out_size, void* d_ws, size_t ws_size,
                              hipStream_t stream) {
    (void)in_sizes; (void)n_in; (void)d_ws; (void)ws_size; (void)out_size;
    const float* x = (const float*)d_in[0];
    const float* y = (const float*)d_in[1];
    float* out = (float*)d_out;
    dtw_fused<<<128, 512, 0, stream>>>(x, y, out);
}

// Round 16
// 178.918 us; speedup vs baseline: 3.2298x; 3.2298x over previous
//
#include <hip/hip_runtime.h>
#include <hip/hip_bf16.h>

#define BIG 1e30f

typedef __attribute__((ext_vector_type(8))) short short8;
typedef __attribute__((ext_vector_type(4))) float f32x4;

#define LGKM_FENCE() do { asm volatile("s_waitcnt lgkmcnt(0)" ::: "memory"); \
                          __builtin_amdgcn_sched_barrier(0); } while (0)
#define SCHED_FENCE() __builtin_amdgcn_sched_barrier(0)

__device__ __forceinline__ unsigned pk_bf16(float lo, float hi) {
    unsigned r;
    asm("v_cvt_pk_bf16_f32 %0, %1, %2" : "=v"(r) : "v"(lo), "v"(hi));
    return r;
}

__device__ __forceinline__ short8 make_frag(float4 a, float4 c) {
    union { unsigned u[4]; short8 s; } cv;
    cv.u[0] = pk_bf16(a.x, a.y);
    cv.u[1] = pk_bf16(a.z, a.w);
    cv.u[2] = pk_bf16(c.x, c.y);
    cv.u[3] = pk_bf16(c.z, c.w);
    return cv.s;
}

// shfl_up(v,1) via DPP wave_shr:1 (validated round 7, absmax 0.0).
__device__ __forceinline__ float dpp_shr1(float v) {
    int o = __builtin_amdgcn_update_dpp(__float_as_int(v), __float_as_int(v),
                                        0x138, 0xf, 0xf, false);
    return __int_as_float(o);
}

// ROUND 16 = r9 (verified 183us, absmax 0.0) composed with two individually
// validated deltas, both REDUCING register pressure:
//  - rowv via readlane conveyor (r14-validated): cv = rowR[1+l] once/stage;
//    step kk uses readlane(cv, kk&63). Removes 128 uniform LDS reads/stage
//    and the rvb[16] buffers (-32 VGPR).
//  - colnext cndmask dropped (r10-validated): act-masking freezes r1 at its
//    c==63 value, so colreg = r1 after the loop.
// dvb LDS ping-pong, fences, GEMM, epilogue, rowW/corner stores: r9 verbatim.
// NO register-stashing of D (r10/r13/r14/r15 all spilled or corrupted).
__global__ __launch_bounds__(512, 1) void dtw_fused(const float* __restrict__ x,
                                                    const float* __restrict__ y,
                                                    float* __restrict__ out)
{
    __shared__ float Dt[8][4096];      // per-wave 64x64 f32 D-tile, XOR-swizzled
    __shared__ float y2s[512];
    __shared__ float rowA[3][8][65];   // [parity][tj][0]=corner, [1+j]=bottom row

    const int b   = blockIdx.x;
    const int tid = threadIdx.x;
    const int w   = tid >> 6;
    const int l   = tid & 63;

    const float* xb = x + (size_t)b * 512 * 64;
    const float* yb = y + (size_t)b * 512 * 64;

    // ---------- prologue: y2, rowA init ----------
    {
        const float4* yr = reinterpret_cast<const float4*>(yb + (size_t)tid * 64);
        float s = 0.f;
        #pragma unroll
        for (int q = 0; q < 16; ++q) {
            float4 v = yr[q];
            s += v.x*v.x + v.y*v.y + v.z*v.z + v.w*v.w;
        }
        y2s[tid] = s;
    }
    for (int i = tid; i < 3*8*65; i += 512) {
        ((float*)rowA)[i] = (i == 2*8*65) ? 0.0f : BIG;
    }

    // ---------- prologue: A fragments (bf16) + x2 ----------
    const int lr = l & 15;
    const int lg = l >> 4;
    short8 afr[4][2];
    float  x2c[4][4];
    {
        float x2f[4];
        #pragma unroll
        for (int mi = 0; mi < 4; ++mi) {
            float part = 0.f;
            #pragma unroll
            for (int ks = 0; ks < 2; ++ks) {
                const float* rp = xb + (size_t)(w*64 + mi*16 + lr) * 64 + ks*32 + lg*8;
                float4 a0 = *reinterpret_cast<const float4*>(rp);
                float4 a1 = *reinterpret_cast<const float4*>(rp + 4);
                afr[mi][ks] = make_frag(a0, a1);
                part += a0.x*a0.x + a0.y*a0.y + a0.z*a0.z + a0.w*a0.w
                      + a1.x*a1.x + a1.y*a1.y + a1.z*a1.z + a1.w*a1.w;
            }
            part += __shfl_xor(part, 16);
            part += __shfl_xor(part, 32);
            x2f[mi] = part;
        }
        #pragma unroll
        for (int mi = 0; mi < 4; ++mi)
            #pragma unroll
            for (int i = 0; i < 4; ++i)
                x2c[mi][i] = __shfl(x2f[mi], lg*4 + i);
    }
    __syncthreads();

    float* Dw = Dt[w];
    const int xr4 = (l & 7) << 2;
    float colreg = BIG;

    #pragma unroll 1
    for (int s = 0; s < 15; ++s) {
        __syncthreads();
        const int tj = s - w;
        if (tj < 0 || tj > 7) continue;
        const int j0 = tj * 64;

        // ---------- GEMM: D-tile via MFMA (r9 verbatim) ----------
        {
            f32x4 acc[4][4] = {};
            #pragma unroll
            for (int ni = 0; ni < 4; ++ni) {
                const float* rp = yb + (size_t)(j0 + ni*16 + lr) * 64 + lg*8;
                float4 b0 = *reinterpret_cast<const float4*>(rp);
                float4 b1 = *reinterpret_cast<const float4*>(rp + 4);
                float4 b2 = *reinterpret_cast<const float4*>(rp + 32);
                float4 b3 = *reinterpret_cast<const float4*>(rp + 36);
                short8 bf0 = make_frag(b0, b1);
                short8 bf1 = make_frag(b2, b3);
                #pragma unroll
                for (int mi = 0; mi < 4; ++mi) {
                    acc[mi][ni] = __builtin_amdgcn_mfma_f32_16x16x32_bf16(afr[mi][0], bf0, acc[mi][ni], 0, 0, 0);
                    acc[mi][ni] = __builtin_amdgcn_mfma_f32_16x16x32_bf16(afr[mi][1], bf1, acc[mi][ni], 0, 0, 0);
                }
            }
            #pragma unroll
            for (int ni = 0; ni < 4; ++ni) {
                float y2v = y2s[j0 + ni*16 + lr];
                #pragma unroll
                for (int mi = 0; mi < 4; ++mi) {
                    #pragma unroll
                    for (int i = 0; i < 4; ++i) {
                        int row = mi*16 + lg*4 + i;
                        int col = ni*16 + lr;
                        Dw[(row*64 + col) ^ ((row & 7) << 2)] = x2c[mi][i] + y2v - 2.0f * acc[mi][ni][i];
                    }
                }
            }
        }

        // ---------- DTW: 128 steps, fence-pinned dv chunks ----------
        const float* rowR = rowA[(s + 2) % 3][tj];
        float*       rowW = rowA[s % 3][tj];

        if (tj == 0 && l == 0) rowW[0] = BIG;

        float cv    = rowR[1 + l];    // conveyor: lane l holds up-row col l
        float saved = rowR[0];        // lane-0 diagonal boundary (corner)
        float r1 = colreg;
        float r2 = BIG;

        auto issue_dv = [&](float (&dvb)[16], int k0) {
            #pragma unroll
            for (int u = 0; u < 16; ++u)
                dvb[u] = Dw[(l << 6) + (((k0 + u - l) & 63) ^ xr4)];
        };
        auto compute16 = [&](float (&dvb)[16], int k0) {
            float rw[16];
            #pragma unroll
            for (int u = 0; u < 16; ++u) {
                int   kk   = k0 + u;
                int   c    = kk - l;
                float rowv = __int_as_float(
                    __builtin_amdgcn_readlane(__float_as_int(cv), kk & 63));
                float dv   = dvb[u];
                float up   = dpp_shr1(r1);
                float dg   = dpp_shr1(r2);
                float pu   = (l == 0) ? rowv  : up;
                float pd   = (l == 0) ? saved : dg;
                float nv   = dv + fminf(fminf(pd, pu), r1);
                bool  act  = ((unsigned)c) < 64u;
                r2 = act ? r1 : r2;
                r1 = act ? nv : r1;      // freezes at c==63 value (r10-validated)
                rw[u] = nv;
                saved = rowv;
            }
            if (l == 63) {
                #pragma unroll
                for (int u = 0; u < 16; ++u) {
                    int kk = k0 + u;
                    if ((unsigned)(kk - 63) < 64u) rowW[kk - 62] = rw[u];
                }
            }
        };

        float dvbA[16], dvbB[16];
        issue_dv(dvbA, 0);
        LGKM_FENCE();
        #pragma unroll 1
        for (int k0 = 0; k0 < 128; k0 += 32) {
            issue_dv(dvbB, k0 + 16);
            SCHED_FENCE();
            compute16(dvbA, k0);
            LGKM_FENCE();
            if (k0 < 96) issue_dv(dvbA, k0 + 32);
            SCHED_FENCE();
            compute16(dvbB, k0 + 16);
            LGKM_FENCE();
        }
        colreg = r1;                    // frozen c==63 value
        if (l == 63 && tj < 7) rowA[(s + 1) % 3][tj + 1][0] = r1;
    }

    if (w == 7 && l == 63) out[b] = colreg;   // R[511][511]
}

extern "C" void kernel_launch(void* const* d_in, const int* in_sizes, int n_in,
                              void* d_out, int out_size, void* d_ws, size_t ws_size,
                              hipStream_t stream) {
    (void)in_sizes; (void)n_in; (void)d_ws; (void)ws_size; (void)out_size;
    const float* x = (const float*)d_in[0];
    const float* y = (const float*)d_in[1];
    float* out = (float*)d_out;
    dtw_fused<<<128, 512, 0, stream>>>(x, y, out);
}

// Round 17
// 146.113 us; speedup vs baseline: 3.9549x; 1.2245x over previous
//
#include <hip/hip_runtime.h>
#include <hip/hip_bf16.h>

#define BIG 1e30f

typedef __attribute__((ext_vector_type(8))) short short8;
typedef __attribute__((ext_vector_type(4))) float f32x4;

__device__ __forceinline__ unsigned pk_bf16(float lo, float hi) {
    unsigned r;
    asm("v_cvt_pk_bf16_f32 %0, %1, %2" : "=v"(r) : "v"(lo), "v"(hi));
    return r;
}

__device__ __forceinline__ short8 make_frag(float4 a, float4 c) {
    union { unsigned u[4]; short8 s; } cv;
    cv.u[0] = pk_bf16(a.x, a.y);
    cv.u[1] = pk_bf16(a.z, a.w);
    cv.u[2] = pk_bf16(c.x, c.y);
    cv.u[3] = pk_bf16(c.z, c.w);
    return cv.s;
}

// lane l <- lane l-1; lane 0 <- oldv. (wave_shr:1 validated r7, absmax 0.0)
__device__ __forceinline__ float dpp_shr1_old(float v, float oldv) {
    int o = __builtin_amdgcn_update_dpp(__float_as_int(oldv), __float_as_int(v),
                                        0x138, 0xf, 0xf, false);
    return __int_as_float(o);
}

// one step of the wave64 inclusive prefix-min ladder (idempotent-safe:
// old=self, bound_ctrl=false -> disabled/invalid lanes contribute v itself)
#define DPPMIN(v, ctrl, rm) do { \
    int _s = __builtin_amdgcn_update_dpp(__float_as_int(v), __float_as_int(v), \
                                         (ctrl), (rm), 0xf, false); \
    (v) = fminf((v), __int_as_float(_s)); } while (0)

// ROUND 17: scan formulation. R[:,j] = S + cummin(a - S) (reference's own
// closed form). Wave 7 = DP: 8 rows/lane, per column: intra-lane Hillis
// prefix-min + 6-step DPP wave ladder; columns sequential (512 chain steps
// total instead of 1920 diagonal steps). Waves 0-6 = producers: MFMA-GEMM
// D into transposed bf16 column-panels [64 cols][512 rows] (one b128/col
// read for DP), double-buffered, one panel ahead; also emit per-8-row
// column sums (psum) so the DP needs no sum-ladder (group prefix computed
// once per panel, lane=column). Sum consistency: colsums use the SAME
// bf16-rounded values the DP unpacks, so S telescopes exactly with d.
__global__ __launch_bounds__(512, 1) void dtw_scan(const float* __restrict__ x,
                                                   const float* __restrict__ y,
                                                   float* __restrict__ out)
{
    __shared__ unsigned short Dp[2][64][520];  // 133 KB: [buf][col][row(+pad)]
    __shared__ float x2s[512], y2s[512];
    __shared__ float psum[64][65];             // [col][group]; pad 65 = no conflicts

    const int b   = blockIdx.x;
    const int tid = threadIdx.x;
    const int w   = tid >> 6;
    const int l   = tid & 63;
    const int lr  = l & 15;
    const int lg  = l >> 4;

    const float* xb = x + (size_t)b * 512 * 64;
    const float* yb = y + (size_t)b * 512 * 64;

    // ---------- prologue: x2s / y2s (one row per thread) ----------
    {
        const float4* xr = reinterpret_cast<const float4*>(xb + (size_t)tid * 64);
        const float4* yr = reinterpret_cast<const float4*>(yb + (size_t)tid * 64);
        float sx = 0.f, sy = 0.f;
        #pragma unroll
        for (int q = 0; q < 16; ++q) {
            float4 vx = xr[q], vy = yr[q];
            sx += vx.x*vx.x + vx.y*vx.y + vx.z*vx.z + vx.w*vx.w;
            sy += vy.x*vy.x + vy.y*vy.y + vy.z*vy.z + vy.w*vy.w;
        }
        x2s[tid] = sx;
        y2s[tid] = sy;
    }
    __syncthreads();

    const int ntile = (w == 6) ? 2 : 1;
    float cs[2][16];   // stashed per-(mi,ni) group colsums (static-indexed)

    // producer: GEMM tile(s) for panel pp -> bf16 transposed panel + colsums
    auto produce = [&](int pp) {
        const int j0 = pp * 64;
        unsigned short (*DBw)[520] = Dp[pp & 1];
        #pragma unroll
        for (int it = 0; it < 2; ++it) {
            if (it < ntile) {
                const int rt = (it == 0) ? w : 7;
                short8 afr[4][2];
                #pragma unroll
                for (int mi = 0; mi < 4; ++mi)
                    #pragma unroll
                    for (int ks = 0; ks < 2; ++ks) {
                        const float* rp = xb + (size_t)(rt*64 + mi*16 + lr) * 64 + ks*32 + lg*8;
                        float4 a0 = *reinterpret_cast<const float4*>(rp);
                        float4 a1 = *reinterpret_cast<const float4*>(rp + 4);
                        afr[mi][ks] = make_frag(a0, a1);
                    }
                f32x4 acc[4][4] = {};
                #pragma unroll
                for (int ni = 0; ni < 4; ++ni) {
                    const float* rp = yb + (size_t)(j0 + ni*16 + lr) * 64 + lg*8;
                    float4 b0 = *reinterpret_cast<const float4*>(rp);
                    float4 b1 = *reinterpret_cast<const float4*>(rp + 4);
                    float4 b2 = *reinterpret_cast<const float4*>(rp + 32);
                    float4 b3 = *reinterpret_cast<const float4*>(rp + 36);
                    short8 bf0 = make_frag(b0, b1);
                    short8 bf1 = make_frag(b2, b3);
                    #pragma unroll
                    for (int mi = 0; mi < 4; ++mi) {
                        acc[mi][ni] = __builtin_amdgcn_mfma_f32_16x16x32_bf16(afr[mi][0], bf0, acc[mi][ni], 0, 0, 0);
                        acc[mi][ni] = __builtin_amdgcn_mfma_f32_16x16x32_bf16(afr[mi][1], bf1, acc[mi][ni], 0, 0, 0);
                    }
                }
                float4 x2q[4];
                #pragma unroll
                for (int mi = 0; mi < 4; ++mi)
                    x2q[mi] = *reinterpret_cast<const float4*>(&x2s[rt*64 + mi*16 + lg*4]);
                #pragma unroll
                for (int ni = 0; ni < 4; ++ni) {
                    float y2v = y2s[j0 + ni*16 + lr];
                    #pragma unroll
                    for (int mi = 0; mi < 4; ++mi) {
                        float dd0 = x2q[mi].x + y2v - 2.0f * acc[mi][ni][0];
                        float dd1 = x2q[mi].y + y2v - 2.0f * acc[mi][ni][1];
                        float dd2 = x2q[mi].z + y2v - 2.0f * acc[mi][ni][2];
                        float dd3 = x2q[mi].w + y2v - 2.0f * acc[mi][ni][3];
                        unsigned w0 = pk_bf16(dd0, dd1);
                        unsigned w1 = pk_bf16(dd2, dd3);
                        uint2 pw; pw.x = w0; pw.y = w1;
                        *reinterpret_cast<uint2*>(&DBw[ni*16 + lr][rt*64 + mi*16 + lg*4]) = pw;
                        // colsum from the ROUNDED values (S must telescope with d)
                        float fa = __uint_as_float(w0 << 16);
                        float fb = __uint_as_float(w0 & 0xffff0000u);
                        float fc = __uint_as_float(w1 << 16);
                        float fd = __uint_as_float(w1 & 0xffff0000u);
                        float s4 = (fa + fb) + (fc + fd);
                        s4 += __shfl_xor(s4, 16);     // lg0+lg1 / lg2+lg3 pairs
                        cs[it][mi*4 + ni] = s4;
                    }
                }
            }
        }
    };

    if (w < 7) produce(0);

    // DP state (wave 7)
    float pR[8];
    #pragma unroll
    for (int r = 0; r < 8; ++r) pR[r] = BIG;
    float bnd  = BIG;
    float bigf = BIG;

    #pragma unroll 1
    for (int p = 0; p < 8; ++p) {
        // phase 1: producers publish panel p's colsums from register stash
        if (w < 7) {
            #pragma unroll
            for (int it = 0; it < 2; ++it) {
                if (it < ntile) {
                    const int rt = (it == 0) ? w : 7;
                    #pragma unroll
                    for (int mi = 0; mi < 4; ++mi)
                        #pragma unroll
                        for (int ni = 0; ni < 4; ++ni)
                            if ((lg & 1) == 0)
                                psum[ni*16 + lr][rt*8 + mi*2 + (lg >> 1)] = cs[it][mi*4 + ni];
                }
            }
        }
        __syncthreads();   // A2: D(p) + psum(p) visible

        if (w == 7) {
            __builtin_amdgcn_s_setprio(1);
            // exclusive group-prefix per column (lane = column, in place)
            {
                float run = 0.f;
                #pragma unroll
                for (int g = 0; g < 64; ++g) {
                    float tmp = psum[l][g];
                    psum[l][g] = run;
                    run += tmp;
                }
            }
            // column scan over this panel
            const unsigned short* DB = &Dp[p & 1][0][0];
            uint4 dc  = *reinterpret_cast<const uint4*>(DB + l*8);
            float pex = psum[0][l];
            #pragma unroll 1
            for (int cl = 0; cl < 64; ++cl) {
                const int cln = (cl < 63) ? cl + 1 : 63;
                uint4 dcn  = *reinterpret_cast<const uint4*>(DB + cln*520 + l*8);
                float pexn = psum[cln][l];

                float d[8], s[8], S[8], f[8], t[8], u1[8], u2[8], q[8];
                d[0] = __uint_as_float(dc.x << 16);
                d[1] = __uint_as_float(dc.x & 0xffff0000u);
                d[2] = __uint_as_float(dc.y << 16);
                d[3] = __uint_as_float(dc.y & 0xffff0000u);
                d[4] = __uint_as_float(dc.z << 16);
                d[5] = __uint_as_float(dc.z & 0xffff0000u);
                d[6] = __uint_as_float(dc.w << 16);
                d[7] = __uint_as_float(dc.w & 0xffff0000u);
                s[0] = d[0];
                #pragma unroll
                for (int r = 1; r < 8; ++r) s[r] = s[r-1] + d[r];
                #pragma unroll
                for (int r = 0; r < 8; ++r) S[r] = pex + s[r];

                float cz  = (p == 0 && cl == 0) ? 0.0f : BIG;
                float b0v = (l == 0) ? cz : bnd;
                f[0] = fminf(b0v, pR[0]);                    // min(diag, left), row 8l
                #pragma unroll
                for (int r = 1; r < 8; ++r) f[r] = fminf(pR[r-1], pR[r]);
                t[0] = f[0] - pex;                           // t[r] = a[r] - S[r] = f[r] - S[r-1]
                #pragma unroll
                for (int r = 1; r < 8; ++r) t[r] = f[r] - S[r-1];

                // intra-lane inclusive prefix-min (3-level Hillis)
                u1[0] = t[0];
                #pragma unroll
                for (int r = 1; r < 8; ++r) u1[r] = fminf(t[r], t[r-1]);
                #pragma unroll
                for (int r = 0; r < 8; ++r) u2[r] = (r >= 2) ? fminf(u1[r], u1[r-2]) : u1[r];
                #pragma unroll
                for (int r = 0; r < 8; ++r) q[r]  = (r >= 4) ? fminf(u2[r], u2[r-4]) : u2[r];

                // cross-lane inclusive prefix-min ladder (wave64)
                float v = q[7];
                DPPMIN(v, 0x111, 0xf);   // row_shr:1
                DPPMIN(v, 0x112, 0xf);   // row_shr:2
                DPPMIN(v, 0x114, 0xf);   // row_shr:4
                DPPMIN(v, 0x118, 0xf);   // row_shr:8
                DPPMIN(v, 0x142, 0xa);   // row_bcast:15 -> rows 1,3
                DPPMIN(v, 0x143, 0xc);   // row_bcast:31 -> rows 2,3
                float e = dpp_shr1_old(v, bigf);   // exclusive (lane0 = BIG)

                #pragma unroll
                for (int r = 0; r < 8; ++r) {
                    float m  = fminf(e, q[r]);
                    float Rv = S[r] + m;
                    pR[r] = Rv;
                }
                bnd = dpp_shr1_old(pR[7], pR[7]);  // lane0 overridden via cz next col
                dc = dcn; pex = pexn;
            }
            __builtin_amdgcn_s_setprio(0);
        } else if (p < 7) {
            produce(p + 1);
        }
        __syncthreads();   // A
    }

    if (w == 7 && l == 63) out[b] = pR[7];   // R[511][511]
}

extern "C" void kernel_launch(void* const* d_in, const int* in_sizes, int n_in,
                              void* d_out, int out_size, void* d_ws, size_t ws_size,
                              hipStream_t stream) {
    (void)in_sizes; (void)n_in; (void)d_ws; (void)ws_size; (void)out_size;
    const float* x = (const float*)d_in[0];
    const float* y = (const float*)d_in[1];
    float* out = (float*)d_out;
    dtw_scan<<<128, 512, 0, stream>>>(x, y, out);
}